// Round 1
// baseline (102.990 us; speedup 1.0000x reference)
//
#include <hip/hip_runtime.h>
#include <hip/hip_bf16.h>
#include <math.h>

// Workspace layout (float offsets)
#define WS_W1T   0        // 256x256 k-major (W1T[k][h] = fc1_w[h][k])
#define WS_W2T   65536    // 256x256 k-major
#define WS_UQ    131072   // 256
#define WS_UK    131328   // 256
#define WS_CONST 131584   // [0]=dq [1]=dk [2]=mlp2_b
#define WS_SQ    131600   // 16384
#define WS_SK    148000   // 16384
// total = 164384 floats = 657,536 bytes

__device__ __forceinline__ float elu1(float x) { return x > 0.f ? x : expm1f(x); }

// ---------------------------------------------------------------------------
// Fold BN + Q/K projections + final dot into per-channel vectors uq/uk and
// scalars dq/dk.  sq_row = dot(x2_row, uq) + dq  (x2 = post-ELU layer-2 out)
// ---------------------------------------------------------------------------
__global__ void prep_scalars(const float* __restrict__ bn_g, const float* __restrict__ bn_b,
                             const float* __restrict__ bn_mean, const float* __restrict__ bn_var,
                             const float* __restrict__ wq_w, const float* __restrict__ wq_b,
                             const float* __restrict__ wk_w, const float* __restrict__ wk_b,
                             const float* __restrict__ mlp2_w, const float* __restrict__ mlp2_b,
                             float* __restrict__ ws) {
    __shared__ float redq[256], redk[256];
    const int h = threadIdx.x;                    // 0..255
    float s  = bn_g[h] * rsqrtf(bn_var[h] + 1e-5f);
    float tt = bn_b[h] - bn_mean[h] * s;
    float vq = 0.f, vk = 0.f;
    #pragma unroll
    for (int d = 0; d < 64; ++d) {
        vq += wq_w[d * 256 + h] * mlp2_w[64 + d];  // wq_half = mlp2_w[0, D:]
        vk += wk_w[d * 256 + h] * mlp2_w[d];       // wk_half = mlp2_w[0, :D]
    }
    ws[WS_UQ + h] = s * vq;
    ws[WS_UK + h] = s * vk;
    redq[h] = tt * vq;
    redk[h] = tt * vk;
    __syncthreads();
    for (int st = 128; st > 0; st >>= 1) {
        if (h < st) { redq[h] += redq[h + st]; redk[h] += redk[h + st]; }
        __syncthreads();
    }
    if (h == 0) {
        float cq = 0.f, ck = 0.f;
        for (int d = 0; d < 64; ++d) {
            cq += wq_b[d] * mlp2_w[64 + d];
            ck += wk_b[d] * mlp2_w[d];
        }
        ws[WS_CONST + 0] = redq[0] + cq;   // dq
        ws[WS_CONST + 1] = redk[0] + ck;   // dk
        ws[WS_CONST + 2] = mlp2_b[0];      // mb
    }
}

// ---------------------------------------------------------------------------
// Transpose fc1_w and fc2_w (256x256) into k-major copies in the workspace so
// the GEMM's weight reads are coalesced float4s.
// blocks 0..15 -> W1 tiles, 16..31 -> W2 tiles (64x64 tiles, 4x4 grid)
// ---------------------------------------------------------------------------
__global__ void transpose2(const float* __restrict__ w1, const float* __restrict__ w2,
                           float* __restrict__ ws) {
    __shared__ float tile[64][65];
    const int bi  = blockIdx.x;
    const float* src = (bi < 16) ? w1 : w2;
    float* dst = ws + ((bi < 16) ? WS_W1T : WS_W2T);
    const int t  = bi & 15;
    const int tr = (t >> 2) * 64, tc = (t & 3) * 64;
    const int tid = threadIdx.x;
    #pragma unroll
    for (int it = 0; it < 16; ++it) {
        int e = it * 256 + tid;
        int r = e >> 6, c = e & 63;
        tile[r][c] = src[(tr + r) * 256 + (tc + c)];
    }
    __syncthreads();
    #pragma unroll
    for (int it = 0; it < 16; ++it) {
        int e = it * 256 + tid;
        int r = e >> 6, c = e & 63;
        dst[(tc + r) * 256 + (tr + c)] = tile[c][r];
    }
}

// ---------------------------------------------------------------------------
// Fused row pipeline: per block, 32 rows.
//   stage inputs -> LDS; GEMM1(+b1,ELU) in regs -> LDS; GEMM2(+b2,ELU) in
//   regs -> dot with uq/uk -> shuffle-reduce -> sq/sk.
// Thread tile: 4 rows x 8 cols.  rg = tid>>5 (row group), cg = tid&31.
// Cols per thread: c = j4*128 + cg*4 + l  (coalesced float4 weight reads).
// ---------------------------------------------------------------------------
__global__ __launch_bounds__(256, 2) void main_rows(const float* __restrict__ inp,
                                                    const float* __restrict__ b1,
                                                    const float* __restrict__ b2,
                                                    float* __restrict__ ws) {
    __shared__ float Ax[32 * 256];   // 32 KB
    float4* Ax4 = (float4*)Ax;
    const int tid = threadIdx.x;
    const int rg = tid >> 5;          // 0..7
    const int cg = tid & 31;          // 0..31
    const int rows0 = blockIdx.x * 32;

    // ---- stage 32 input rows (coalesced float4) ----
    const float4* inp4 = (const float4*)(inp + (size_t)rows0 * 256);
    #pragma unroll
    for (int it = 0; it < 8; ++it) {
        int f4 = it * 256 + tid;      // 0..2047
        Ax4[f4] = inp4[f4];
    }
    __syncthreads();

    const float4* W1T4 = (const float4*)(ws + WS_W1T);
    const float4* W2T4 = (const float4*)(ws + WS_W2T);

    float acc[4][8];

    // ================= phase 1: h1 = elu(A @ W1^T + b1) =================
    #pragma unroll
    for (int i = 0; i < 4; ++i)
        #pragma unroll
        for (int j = 0; j < 8; ++j) acc[i][j] = 0.f;

    for (int k = 0; k < 256; k += 4) {
        float4 av[4];
        #pragma unroll
        for (int i = 0; i < 4; ++i) av[i] = Ax4[(rg * 4 + i) * 64 + (k >> 2)];
        #pragma unroll
        for (int kk = 0; kk < 4; ++kk) {
            float4 w0 = W1T4[(k + kk) * 64 + cg];
            float4 w1 = W1T4[(k + kk) * 64 + 32 + cg];
            #pragma unroll
            for (int i = 0; i < 4; ++i) {
                float a = (kk == 0) ? av[i].x : (kk == 1) ? av[i].y : (kk == 2) ? av[i].z : av[i].w;
                acc[i][0] += a * w0.x; acc[i][1] += a * w0.y;
                acc[i][2] += a * w0.z; acc[i][3] += a * w0.w;
                acc[i][4] += a * w1.x; acc[i][5] += a * w1.y;
                acc[i][6] += a * w1.z; acc[i][7] += a * w1.w;
            }
        }
    }

    {
        float4 bb0 = ((const float4*)b1)[cg];
        float4 bb1 = ((const float4*)b1)[32 + cg];
        #pragma unroll
        for (int i = 0; i < 4; ++i) {
            acc[i][0] = elu1(acc[i][0] + bb0.x); acc[i][1] = elu1(acc[i][1] + bb0.y);
            acc[i][2] = elu1(acc[i][2] + bb0.z); acc[i][3] = elu1(acc[i][3] + bb0.w);
            acc[i][4] = elu1(acc[i][4] + bb1.x); acc[i][5] = elu1(acc[i][5] + bb1.y);
            acc[i][6] = elu1(acc[i][6] + bb1.z); acc[i][7] = elu1(acc[i][7] + bb1.w);
        }
    }
    __syncthreads();   // everyone done reading inputs from Ax

    // write h1 into Ax (same layout)
    #pragma unroll
    for (int i = 0; i < 4; ++i) {
        Ax4[(rg * 4 + i) * 64 + cg]      = make_float4(acc[i][0], acc[i][1], acc[i][2], acc[i][3]);
        Ax4[(rg * 4 + i) * 64 + 32 + cg] = make_float4(acc[i][4], acc[i][5], acc[i][6], acc[i][7]);
    }
    __syncthreads();

    // ================= phase 2: z2 = h1 @ W2^T + b2; dots =================
    #pragma unroll
    for (int i = 0; i < 4; ++i)
        #pragma unroll
        for (int j = 0; j < 8; ++j) acc[i][j] = 0.f;

    for (int k = 0; k < 256; k += 4) {
        float4 av[4];
        #pragma unroll
        for (int i = 0; i < 4; ++i) av[i] = Ax4[(rg * 4 + i) * 64 + (k >> 2)];
        #pragma unroll
        for (int kk = 0; kk < 4; ++kk) {
            float4 w0 = W2T4[(k + kk) * 64 + cg];
            float4 w1 = W2T4[(k + kk) * 64 + 32 + cg];
            #pragma unroll
            for (int i = 0; i < 4; ++i) {
                float a = (kk == 0) ? av[i].x : (kk == 1) ? av[i].y : (kk == 2) ? av[i].z : av[i].w;
                acc[i][0] += a * w0.x; acc[i][1] += a * w0.y;
                acc[i][2] += a * w0.z; acc[i][3] += a * w0.w;
                acc[i][4] += a * w1.x; acc[i][5] += a * w1.y;
                acc[i][6] += a * w1.z; acc[i][7] += a * w1.w;
            }
        }
    }

    float sqp[4], skp[4];
    {
        float4 bb0 = ((const float4*)b2)[cg];
        float4 bb1 = ((const float4*)b2)[32 + cg];
        float4 uq0 = ((const float4*)(ws + WS_UQ))[cg];
        float4 uq1 = ((const float4*)(ws + WS_UQ))[32 + cg];
        float4 uk0 = ((const float4*)(ws + WS_UK))[cg];
        float4 uk1 = ((const float4*)(ws + WS_UK))[32 + cg];
        #pragma unroll
        for (int i = 0; i < 4; ++i) {
            float v0 = elu1(acc[i][0] + bb0.x), v1 = elu1(acc[i][1] + bb0.y);
            float v2 = elu1(acc[i][2] + bb0.z), v3 = elu1(acc[i][3] + bb0.w);
            float v4 = elu1(acc[i][4] + bb1.x), v5 = elu1(acc[i][5] + bb1.y);
            float v6 = elu1(acc[i][6] + bb1.z), v7 = elu1(acc[i][7] + bb1.w);
            sqp[i] = v0 * uq0.x + v1 * uq0.y + v2 * uq0.z + v3 * uq0.w
                   + v4 * uq1.x + v5 * uq1.y + v6 * uq1.z + v7 * uq1.w;
            skp[i] = v0 * uk0.x + v1 * uk0.y + v2 * uk0.z + v3 * uk0.w
                   + v4 * uk1.x + v5 * uk1.y + v6 * uk1.z + v7 * uk1.w;
        }
    }
    // reduce across the 32 col-group lanes (masks 1..16 never cross the
    // 32-lane boundary, so plain wave64 shfl_xor is safe)
    #pragma unroll
    for (int m = 16; m >= 1; m >>= 1) {
        #pragma unroll
        for (int i = 0; i < 4; ++i) {
            sqp[i] += __shfl_xor(sqp[i], m);
            skp[i] += __shfl_xor(skp[i], m);
        }
    }
    if (cg == 0) {
        float dq = ws[WS_CONST + 0];
        float dk = ws[WS_CONST + 1];
        #pragma unroll
        for (int i = 0; i < 4; ++i) {
            int r = rows0 + rg * 4 + i;
            ws[WS_SQ + r] = sqp[i] + dq;
            ws[WS_SK + r] = skp[i] + dk;
        }
    }
}

// ---------------------------------------------------------------------------
// probs[b,i,j] = sq[b,i] + sk[b,j] + mb   (134 MB write, memory-bound)
// One block: 8 output rows of one b.  sk row staged in LDS.
// ---------------------------------------------------------------------------
__global__ __launch_bounds__(256) void broadcast_out(const float* __restrict__ ws,
                                                     float* __restrict__ out) {
    __shared__ float skL[2048];
    const int bi = blockIdx.x;
    const int b = bi >> 8;             // 0..7
    const int chunk = bi & 255;        // 0..255
    const int tid = threadIdx.x;

    float4* skL4 = (float4*)skL;
    const float4* skb4 = (const float4*)(ws + WS_SK + b * 2048);
    #pragma unroll
    for (int it = 0; it < 2; ++it) skL4[it * 256 + tid] = skb4[it * 256 + tid];
    __syncthreads();

    const float mb = ws[WS_CONST + 2];
    const int i0 = chunk * 8;
    #pragma unroll
    for (int i = 0; i < 8; ++i) {
        float sval = ws[WS_SQ + b * 2048 + i0 + i] + mb;
        float4* orow = (float4*)(out + ((size_t)(b * 2048 + i0 + i)) * 2048);
        #pragma unroll
        for (int h = 0; h < 2; ++h) {
            int j4 = h * 256 + tid;
            float4 v = skL4[j4];
            orow[j4] = make_float4(sval + v.x, sval + v.y, sval + v.z, sval + v.w);
        }
    }
}

// ---------------------------------------------------------------------------
extern "C" void kernel_launch(void* const* d_in, const int* in_sizes, int n_in,
                              void* d_out, int out_size, void* d_ws, size_t ws_size,
                              hipStream_t stream) {
    const float* inputs  = (const float*)d_in[0];
    const float* fc1_w   = (const float*)d_in[1];
    const float* fc1_b   = (const float*)d_in[2];
    const float* fc2_w   = (const float*)d_in[3];
    const float* fc2_b   = (const float*)d_in[4];
    const float* bn_g    = (const float*)d_in[5];
    const float* bn_b    = (const float*)d_in[6];
    const float* bn_mean = (const float*)d_in[7];
    const float* bn_var  = (const float*)d_in[8];
    const float* wq_w    = (const float*)d_in[9];
    const float* wq_b    = (const float*)d_in[10];
    const float* wk_w    = (const float*)d_in[11];
    const float* wk_b    = (const float*)d_in[12];
    const float* mlp2_w  = (const float*)d_in[13];
    const float* mlp2_b  = (const float*)d_in[14];
    float* ws  = (float*)d_ws;
    float* out = (float*)d_out;

    hipLaunchKernelGGL(prep_scalars, dim3(1), dim3(256), 0, stream,
                       bn_g, bn_b, bn_mean, bn_var, wq_w, wq_b, wk_w, wk_b,
                       mlp2_w, mlp2_b, ws);
    hipLaunchKernelGGL(transpose2, dim3(32), dim3(256), 0, stream, fc1_w, fc2_w, ws);
    hipLaunchKernelGGL(main_rows, dim3(512), dim3(256), 0, stream,
                       inputs, fc1_b, fc2_b, ws);
    hipLaunchKernelGGL(broadcast_out, dim3(2048), dim3(256), 0, stream, ws, out);
}

// Round 2
// 64.246 us; speedup vs baseline: 1.6031x; 1.6031x over previous
//
#include <hip/hip_runtime.h>
#include <hip/hip_bf16.h>
#include <math.h>

typedef __bf16 bf16x8 __attribute__((ext_vector_type(8)));
typedef float  f32x4  __attribute__((ext_vector_type(4)));

// Workspace layout (float-index offsets)
#define WS_STG1  0        // W1 staged bf16 hi/lo, swizzled, 8 kt-slices x 32KB = 256KB
#define WS_STG2  65536    // W2 staged, 256KB
#define WS_UQ    131072   // 256 f32
#define WS_UK    131328   // 256 f32
#define WS_CONST 131584   // [0]=dq [1]=dk [2]=mlp2_b
#define WS_SQ    131600   // 16384 f32
#define WS_SK    148000   // 16384 f32

__device__ __forceinline__ void gload16(const void* g, void* l) {
    __builtin_amdgcn_global_load_lds((const __attribute__((address_space(1))) void*)g,
                                     (__attribute__((address_space(3))) void*)l,
                                     16, 0, 0);
}

// ---------------------------------------------------------------------------
// Fold BN + Q/K projections + final dot into uq/uk (per-channel) and dq/dk.
// sq_row = dot(x2_row, uq) + dq   (x2 = post-ELU layer-2 output)
// ---------------------------------------------------------------------------
__global__ void prep_scalars(const float* __restrict__ bn_g, const float* __restrict__ bn_b,
                             const float* __restrict__ bn_mean, const float* __restrict__ bn_var,
                             const float* __restrict__ wq_w, const float* __restrict__ wq_b,
                             const float* __restrict__ wk_w, const float* __restrict__ wk_b,
                             const float* __restrict__ mlp2_w, const float* __restrict__ mlp2_b,
                             float* __restrict__ ws) {
    __shared__ float redq[256], redk[256];
    const int h = threadIdx.x;
    float s  = bn_g[h] * rsqrtf(bn_var[h] + 1e-5f);
    float tt = bn_b[h] - bn_mean[h] * s;
    float vq = 0.f, vk = 0.f;
    #pragma unroll
    for (int d = 0; d < 64; ++d) {
        vq += wq_w[d * 256 + h] * mlp2_w[64 + d];  // wq_half = mlp2_w[0, D:]
        vk += wk_w[d * 256 + h] * mlp2_w[d];       // wk_half = mlp2_w[0, :D]
    }
    ws[WS_UQ + h] = s * vq;
    ws[WS_UK + h] = s * vk;
    redq[h] = tt * vq;
    redk[h] = tt * vk;
    __syncthreads();
    for (int st = 128; st > 0; st >>= 1) {
        if (h < st) { redq[h] += redq[h + st]; redk[h] += redk[h + st]; }
        __syncthreads();
    }
    if (h == 0) {
        float cq = 0.f, ck = 0.f;
        for (int d = 0; d < 64; ++d) {
            cq += wq_b[d] * mlp2_w[64 + d];
            ck += wk_b[d] * mlp2_w[d];
        }
        ws[WS_CONST + 0] = redq[0] + cq;
        ws[WS_CONST + 1] = redk[0] + ck;
        ws[WS_CONST + 2] = mlp2_b[0];
    }
}

// ---------------------------------------------------------------------------
// Split W (fp32) into bf16 hi + lo and store in ws, arranged per kt-slice in
// the exact (swizzled) LDS byte order so main's global_load_lds is a linear
// byte copy.  chunk byte offset within 16KB half: (n*64 + c*16) ^ ((n&7)<<4)
// holds W[n][kt*32 + c*8 .. +7].
// grid: 16 blocks (bit3: 0=W1 1=W2, bits0-2: kt), 256 threads (n).
// ---------------------------------------------------------------------------
__global__ void prep_weights(const float* __restrict__ w1, const float* __restrict__ w2,
                             float* __restrict__ ws) {
    const int m  = blockIdx.x >> 3;
    const int kt = blockIdx.x & 7;
    const int n  = threadIdx.x;
    const float* src = m ? w2 : w1;
    char* dst = (char*)(ws + (m ? WS_STG2 : WS_STG1)) + kt * 32768;
    #pragma unroll
    for (int c = 0; c < 4; ++c) {
        bf16x8 hi, lo;
        #pragma unroll
        for (int j = 0; j < 8; ++j) {
            float v = src[n * 256 + kt * 32 + c * 8 + j];
            __bf16 hb = (__bf16)v;
            hi[j] = hb;
            lo[j] = (__bf16)(v - (float)hb);
        }
        int ob = (n * 64 + c * 16) ^ ((n & 7) << 4);
        *(bf16x8*)(dst + ob)         = hi;
        *(bf16x8*)(dst + 16384 + ob) = lo;
    }
}

// ---------------------------------------------------------------------------
// Fused 2-layer MLP via split-bf16 MFMA + per-row dot epilogue.
// 512 blocks x 256 thr (4 waves), 32 rows/block.
// wave w: p=w&1 (row tile of 16), h=w>>1 (N-half, 8 n-tiles of 16).
// lane: lr=l&15, lk=l>>4.  MFMA 16x16x32 bf16:
//   A frag: A[lr][kt*32+lk*8+j]; B frag: W[n=lr][kt*32+lk*8+j]; D: row=lk*4+r, col=lr.
// ---------------------------------------------------------------------------
__global__ __launch_bounds__(256, 2) void main_mfma(const float* __restrict__ inp,
                                                    const float* __restrict__ b1,
                                                    const float* __restrict__ b2,
                                                    float* __restrict__ ws) {
    __shared__ float  X1s[8192];     // 32KB: x1 fp32 [32 rows][256], swizzled
    __shared__ __bf16 Wb[16384];     // 32KB: staged W kt-slice (hi 16KB | lo 16KB)

    const int tid = threadIdx.x;
    const int l   = tid & 63;
    const int w   = tid >> 6;
    const int p   = w & 1;
    const int h   = w >> 1;
    const int lr  = l & 15;
    const int lk  = l >> 4;
    const int rows0 = blockIdx.x * 32;

    const __bf16* stg1 = (const __bf16*)(ws + WS_STG1);
    const __bf16* stg2 = (const __bf16*)(ws + WS_STG2);

    f32x4 acc[8];

    // ================= phase 1: x1 = elu(A @ W1^T + b1) =================
    #pragma unroll
    for (int nt = 0; nt < 8; ++nt) acc[nt] = (f32x4)0.f;

    for (int kt = 0; kt < 8; ++kt) {
        __syncthreads();                       // prev kt's Wb reads done
        {
            const __bf16* src = stg1 + kt * 16384;
            #pragma unroll
            for (int j = 0; j < 8; ++j) {
                int ch = (w * 8 + j) * 64 + l;
                gload16(src + ch * 8, Wb + ch * 8);
            }
        }
        const int row = rows0 + p * 16 + lr;
        const float4* ap = (const float4*)(inp + (size_t)row * 256 + kt * 32 + lk * 8);
        float4 f0 = ap[0], f1 = ap[1];         // in flight across the barrier drain
        __syncthreads();                       // stage visible
        bf16x8 ah, al;
        {
            float fv[8] = {f0.x,f0.y,f0.z,f0.w,f1.x,f1.y,f1.z,f1.w};
            #pragma unroll
            for (int j = 0; j < 8; ++j) { __bf16 hv=(__bf16)fv[j]; ah[j]=hv; al[j]=(__bf16)(fv[j]-(float)hv); }
        }
        #pragma unroll
        for (int nt = 0; nt < 8; ++nt) {
            int n  = h * 128 + nt * 16 + lr;
            int ob = (n * 64 + lk * 16) ^ ((n & 7) << 4);
            bf16x8 bh = *(const bf16x8*)((const char*)Wb + ob);
            bf16x8 bl = *(const bf16x8*)((const char*)Wb + 16384 + ob);
            acc[nt] = __builtin_amdgcn_mfma_f32_16x16x32_bf16(ah, bh, acc[nt], 0, 0, 0);
            acc[nt] = __builtin_amdgcn_mfma_f32_16x16x32_bf16(al, bh, acc[nt], 0, 0, 0);
            acc[nt] = __builtin_amdgcn_mfma_f32_16x16x32_bf16(ah, bl, acc[nt], 0, 0, 0);
        }
    }
    // epilogue 1: bias + elu -> X1s (fp32, swizzled rows of 1KB)
    #pragma unroll
    for (int nt = 0; nt < 8; ++nt) {
        int col = h * 128 + nt * 16 + lr;
        float bb = b1[col];
        #pragma unroll
        for (int r = 0; r < 4; ++r) {
            int rr = p * 16 + lk * 4 + r;
            float v = acc[nt][r] + bb;
            v = v > 0.f ? v : expm1f(v);
            int ob = (rr * 1024 + col * 4) ^ ((rr & 7) << 4);
            *(float*)((char*)X1s + ob) = v;
        }
    }

    // ================= phase 2: z2 = x1 @ W2^T + b2 =================
    #pragma unroll
    for (int nt = 0; nt < 8; ++nt) acc[nt] = (f32x4)0.f;

    for (int kt = 0; kt < 8; ++kt) {
        __syncthreads();                       // X1 visible (kt=0) / Wb reads done
        {
            const __bf16* src = stg2 + kt * 16384;
            #pragma unroll
            for (int j = 0; j < 8; ++j) {
                int ch = (w * 8 + j) * 64 + l;
                gload16(src + ch * 8, Wb + ch * 8);
            }
        }
        const int rr = p * 16 + lr;
        int ob1 = (rr * 1024 + kt * 128 + lk * 32) ^ ((rr & 7) << 4);
        float4 x0  = *(const float4*)((const char*)X1s + ob1);
        float4 x1v = *(const float4*)((const char*)X1s + (ob1 ^ 16));
        __syncthreads();                       // stage visible
        bf16x8 ah, al;
        {
            float fv[8] = {x0.x,x0.y,x0.z,x0.w,x1v.x,x1v.y,x1v.z,x1v.w};
            #pragma unroll
            for (int j = 0; j < 8; ++j) { __bf16 hv=(__bf16)fv[j]; ah[j]=hv; al[j]=(__bf16)(fv[j]-(float)hv); }
        }
        #pragma unroll
        for (int nt = 0; nt < 8; ++nt) {
            int n  = h * 128 + nt * 16 + lr;
            int ob = (n * 64 + lk * 16) ^ ((n & 7) << 4);
            bf16x8 bh = *(const bf16x8*)((const char*)Wb + ob);
            bf16x8 bl = *(const bf16x8*)((const char*)Wb + 16384 + ob);
            acc[nt] = __builtin_amdgcn_mfma_f32_16x16x32_bf16(ah, bh, acc[nt], 0, 0, 0);
            acc[nt] = __builtin_amdgcn_mfma_f32_16x16x32_bf16(al, bh, acc[nt], 0, 0, 0);
            acc[nt] = __builtin_amdgcn_mfma_f32_16x16x32_bf16(ah, bl, acc[nt], 0, 0, 0);
        }
    }
    // epilogue 2: bias + elu, dot with uq/uk, reduce, write sq/sk
    float sqp[4] = {0.f,0.f,0.f,0.f}, skp[4] = {0.f,0.f,0.f,0.f};
    const float* uq = ws + WS_UQ;
    const float* uk = ws + WS_UK;
    #pragma unroll
    for (int nt = 0; nt < 8; ++nt) {
        int col = h * 128 + nt * 16 + lr;
        float bb = b2[col], qc = uq[col], kc = uk[col];
        #pragma unroll
        for (int r = 0; r < 4; ++r) {
            float v = acc[nt][r] + bb;
            v = v > 0.f ? v : expm1f(v);
            sqp[r] += v * qc;
            skp[r] += v * kc;
        }
    }
    #pragma unroll
    for (int mm = 8; mm >= 1; mm >>= 1) {      // reduce over lr (within 16-lane groups)
        #pragma unroll
        for (int r = 0; r < 4; ++r) {
            sqp[r] += __shfl_xor(sqp[r], mm);
            skp[r] += __shfl_xor(skp[r], mm);
        }
    }
    __syncthreads();                           // Wb free -> reuse as reduction buffer
    float* red = (float*)Wb;                   // [0..63]=q (h0|h1 x32), [64..127]=k
    if (lr == 0) {
        #pragma unroll
        for (int r = 0; r < 4; ++r) {
            int rl = p * 16 + lk * 4 + r;
            red[h * 32 + rl]      = sqp[r];
            red[64 + h * 32 + rl] = skp[r];
        }
    }
    __syncthreads();
    if (tid < 32) {
        float dq = ws[WS_CONST + 0];
        ws[WS_SQ + rows0 + tid] = red[tid] + red[32 + tid] + dq;
    } else if (tid < 64) {
        int rl = tid - 32;
        float dk = ws[WS_CONST + 1];
        ws[WS_SK + rows0 + rl] = red[64 + rl] + red[96 + rl] + dk;
    }
}

// ---------------------------------------------------------------------------
// probs[b,i,j] = sq[b,i] + sk[b,j] + mb   (134 MB write, memory-bound)
// ---------------------------------------------------------------------------
__global__ __launch_bounds__(256) void broadcast_out(const float* __restrict__ ws,
                                                     float* __restrict__ out) {
    __shared__ float skL[2048];
    const int bi = blockIdx.x;
    const int b = bi >> 8;
    const int chunk = bi & 255;
    const int tid = threadIdx.x;

    float4* skL4 = (float4*)skL;
    const float4* skb4 = (const float4*)(ws + WS_SK + b * 2048);
    #pragma unroll
    for (int it = 0; it < 2; ++it) skL4[it * 256 + tid] = skb4[it * 256 + tid];
    __syncthreads();

    const float mb = ws[WS_CONST + 2];
    const int i0 = chunk * 8;
    #pragma unroll
    for (int i = 0; i < 8; ++i) {
        float sval = ws[WS_SQ + b * 2048 + i0 + i] + mb;
        float4* orow = (float4*)(out + ((size_t)(b * 2048 + i0 + i)) * 2048);
        #pragma unroll
        for (int hh = 0; hh < 2; ++hh) {
            int j4 = hh * 256 + tid;
            float4 v = skL4[j4];
            orow[j4] = make_float4(sval + v.x, sval + v.y, sval + v.z, sval + v.w);
        }
    }
}

// ---------------------------------------------------------------------------
extern "C" void kernel_launch(void* const* d_in, const int* in_sizes, int n_in,
                              void* d_out, int out_size, void* d_ws, size_t ws_size,
                              hipStream_t stream) {
    const float* inputs  = (const float*)d_in[0];
    const float* fc1_w   = (const float*)d_in[1];
    const float* fc1_b   = (const float*)d_in[2];
    const float* fc2_w   = (const float*)d_in[3];
    const float* fc2_b   = (const float*)d_in[4];
    const float* bn_g    = (const float*)d_in[5];
    const float* bn_b    = (const float*)d_in[6];
    const float* bn_mean = (const float*)d_in[7];
    const float* bn_var  = (const float*)d_in[8];
    const float* wq_w    = (const float*)d_in[9];
    const float* wq_b    = (const float*)d_in[10];
    const float* wk_w    = (const float*)d_in[11];
    const float* wk_b    = (const float*)d_in[12];
    const float* mlp2_w  = (const float*)d_in[13];
    const float* mlp2_b  = (const float*)d_in[14];
    float* ws  = (float*)d_ws;
    float* out = (float*)d_out;

    hipLaunchKernelGGL(prep_scalars, dim3(1), dim3(256), 0, stream,
                       bn_g, bn_b, bn_mean, bn_var, wq_w, wq_b, wk_w, wk_b,
                       mlp2_w, mlp2_b, ws);
    hipLaunchKernelGGL(prep_weights, dim3(16), dim3(256), 0, stream, fc1_w, fc2_w, ws);
    hipLaunchKernelGGL(main_mfma, dim3(512), dim3(256), 0, stream,
                       inputs, fc1_b, fc2_b, ws);
    hipLaunchKernelGGL(broadcast_out, dim3(2048), dim3(256), 0, stream, ws, out);
}

// Round 3
// 58.815 us; speedup vs baseline: 1.7511x; 1.0923x over previous
//
#include <hip/hip_runtime.h>
#include <hip/hip_bf16.h>
#include <math.h>

typedef __bf16 bf16x8 __attribute__((ext_vector_type(8)));
typedef float  f32x4  __attribute__((ext_vector_type(4)));

// Workspace layout (float-index offsets)
// W staged as bf16 hi(128KB)+lo(128KB) per matrix, in MFMA-fragment chunk
// order: chunk c = kt*16 + ntile (1KB), byte l*16 inside chunk = lane l's
// B-fragment = W[ntile*16 + (l&15)][kt*32 + (l>>4)*8 .. +7]
#define WS_STG1  0        // 65536 floats (256KB)
#define WS_STG2  65536    // 65536 floats (256KB)
#define WS_UQ    131072   // 256 f32
#define WS_UK    131328   // 256 f32
#define WS_CONST 131584   // [0]=dq [1]=dk [2]=mlp2_b
#define WS_SQ    131600   // 16384 f32
#define WS_SK    148000   // 16384 f32

__device__ __forceinline__ float elu1(float x) { return x > 0.f ? x : expm1f(x); }

// ---------------------------------------------------------------------------
// block 0: fold BN + Q/K + final dot into uq/uk, dq/dk.
// blocks 1..16: split W1/W2 into bf16 hi/lo in fragment-chunk order.
// ---------------------------------------------------------------------------
__global__ void prep_all(const float* __restrict__ w1, const float* __restrict__ w2,
                         const float* __restrict__ bn_g, const float* __restrict__ bn_b,
                         const float* __restrict__ bn_mean, const float* __restrict__ bn_var,
                         const float* __restrict__ wq_w, const float* __restrict__ wq_b,
                         const float* __restrict__ wk_w, const float* __restrict__ wk_b,
                         const float* __restrict__ mlp2_w, const float* __restrict__ mlp2_b,
                         float* __restrict__ ws) {
    if (blockIdx.x == 0) {
        __shared__ float redq[256], redk[256];
        const int h = threadIdx.x;
        float s  = bn_g[h] * rsqrtf(bn_var[h] + 1e-5f);
        float tt = bn_b[h] - bn_mean[h] * s;
        float vq = 0.f, vk = 0.f;
        #pragma unroll
        for (int d = 0; d < 64; ++d) {
            vq += wq_w[d * 256 + h] * mlp2_w[64 + d];  // wq_half = mlp2_w[0, D:]
            vk += wk_w[d * 256 + h] * mlp2_w[d];       // wk_half = mlp2_w[0, :D]
        }
        ws[WS_UQ + h] = s * vq;
        ws[WS_UK + h] = s * vk;
        redq[h] = tt * vq;
        redk[h] = tt * vk;
        __syncthreads();
        for (int st = 128; st > 0; st >>= 1) {
            if (h < st) { redq[h] += redq[h + st]; redk[h] += redk[h + st]; }
            __syncthreads();
        }
        if (h == 0) {
            float cq = 0.f, ck = 0.f;
            for (int d = 0; d < 64; ++d) {
                cq += wq_b[d] * mlp2_w[64 + d];
                ck += wk_b[d] * mlp2_w[d];
            }
            ws[WS_CONST + 0] = redq[0] + cq;
            ws[WS_CONST + 1] = redk[0] + ck;
            ws[WS_CONST + 2] = mlp2_b[0];
        }
        return;
    }
    // ---- weight split ----
    const int bid = blockIdx.x - 1;
    const int m   = bid >> 3;
    const int kt  = bid & 7;
    const float* src = m ? w2 : w1;
    __bf16* stgh = (__bf16*)(ws + (m ? WS_STG2 : WS_STG1));
    __bf16* stgl = stgh + 65536;
    const int tid = threadIdx.x;
    #pragma unroll
    for (int it = 0; it < 4; ++it) {
        int idx = it * 256 + tid;          // 0..1023 = nt*64 + l
        int nt = idx >> 6, l = idx & 63;
        int lr = l & 15, lk = l >> 4;
        const float* sp = src + (nt * 16 + lr) * 256 + kt * 32 + lk * 8;
        bf16x8 hi, lo;
        #pragma unroll
        for (int j = 0; j < 8; ++j) {
            float v = sp[j];
            __bf16 hb = (__bf16)v;
            hi[j] = hb;
            lo[j] = (__bf16)(v - (float)hb);
        }
        int off = (kt * 16 + nt) * 512 + l * 8;
        *(bf16x8*)(stgh + off) = hi;
        *(bf16x8*)(stgl + off) = lo;
    }
}

// ---------------------------------------------------------------------------
// Fused 2-layer MLP, split-bf16 MFMA, B-fragments straight from L2 (no W
// staging, no per-kt barriers).  512 blocks x 256 thr; 32 rows/block.
// wave w owns n-quarter [w*64, w*64+64), 2 row-tiles x 4 n-tiles.
// lane: lr=l&15 lk=l>>4.  16x16x32 frags:
//   A: A[lr][kt*32+lk*8+j]   B: W[n0+nt*16+lr][kt*32+lk*8+j]
//   D: row=lk*4+r, col=lr
// ---------------------------------------------------------------------------
__global__ __launch_bounds__(256, 2) void main_mfma(const float* __restrict__ inp,
                                                    const float* __restrict__ b1,
                                                    const float* __restrict__ b2,
                                                    float* __restrict__ ws) {
    __shared__ float X1s[8192];      // 32KB: x1 fp32 [32 rows][256], swizzled
    __shared__ float redq[128], redk[128];

    const int tid = threadIdx.x;
    const int l   = tid & 63;
    const int w   = tid >> 6;        // n-quarter
    const int lr  = l & 15;
    const int lk  = l >> 4;
    const int rows0 = blockIdx.x * 32;
    const int n0  = w * 64;

    const __bf16* s1 = (const __bf16*)(ws + WS_STG1);
    const __bf16* s2 = (const __bf16*)(ws + WS_STG2);

    f32x4 acc[2][4];

    // ================= phase 1: x1 = elu(A @ W1^T + b1) =================
    #pragma unroll
    for (int p = 0; p < 2; ++p)
        #pragma unroll
        for (int nt = 0; nt < 4; ++nt) acc[p][nt] = (f32x4)0.f;

    #pragma unroll 2
    for (int kt = 0; kt < 8; ++kt) {
        bf16x8 bh[4], bl[4];
        #pragma unroll
        for (int nt = 0; nt < 4; ++nt) {
            const __bf16* bp = s1 + ((kt * 16 + w * 4 + nt) << 9) + l * 8;
            bh[nt] = *(const bf16x8*)bp;
            bl[nt] = *(const bf16x8*)(bp + 65536);
        }
        bf16x8 ah[2], al[2];
        #pragma unroll
        for (int p = 0; p < 2; ++p) {
            const float4* ap = (const float4*)(inp + (size_t)(rows0 + p * 16 + lr) * 256 + kt * 32 + lk * 8);
            float4 f0 = ap[0], f1 = ap[1];
            float fv[8] = {f0.x,f0.y,f0.z,f0.w,f1.x,f1.y,f1.z,f1.w};
            #pragma unroll
            for (int j = 0; j < 8; ++j) { __bf16 hv=(__bf16)fv[j]; ah[p][j]=hv; al[p][j]=(__bf16)(fv[j]-(float)hv); }
        }
        #pragma unroll
        for (int p = 0; p < 2; ++p)
            #pragma unroll
            for (int nt = 0; nt < 4; ++nt) {
                acc[p][nt] = __builtin_amdgcn_mfma_f32_16x16x32_bf16(ah[p], bh[nt], acc[p][nt], 0, 0, 0);
                acc[p][nt] = __builtin_amdgcn_mfma_f32_16x16x32_bf16(al[p], bh[nt], acc[p][nt], 0, 0, 0);
                acc[p][nt] = __builtin_amdgcn_mfma_f32_16x16x32_bf16(ah[p], bl[nt], acc[p][nt], 0, 0, 0);
            }
    }
    // epilogue 1: bias + elu -> X1s (swizzled)
    #pragma unroll
    for (int p = 0; p < 2; ++p)
        #pragma unroll
        for (int nt = 0; nt < 4; ++nt) {
            int col = n0 + nt * 16 + lr;
            float bb = b1[col];
            #pragma unroll
            for (int r = 0; r < 4; ++r) {
                int rr = p * 16 + lk * 4 + r;
                float v = elu1(acc[p][nt][r] + bb);
                int ob = (rr * 1024 + col * 4) ^ ((rr & 7) << 4);
                *(float*)((char*)X1s + ob) = v;
            }
        }
    __syncthreads();

    // ================= phase 2: z2 = x1 @ W2^T + b2 =================
    #pragma unroll
    for (int p = 0; p < 2; ++p)
        #pragma unroll
        for (int nt = 0; nt < 4; ++nt) acc[p][nt] = (f32x4)0.f;

    #pragma unroll 2
    for (int kt = 0; kt < 8; ++kt) {
        bf16x8 bh[4], bl[4];
        #pragma unroll
        for (int nt = 0; nt < 4; ++nt) {
            const __bf16* bp = s2 + ((kt * 16 + w * 4 + nt) << 9) + l * 8;
            bh[nt] = *(const bf16x8*)bp;
            bl[nt] = *(const bf16x8*)(bp + 65536);
        }
        bf16x8 ah[2], al[2];
        #pragma unroll
        for (int p = 0; p < 2; ++p) {
            int rr = p * 16 + lr;
            int ob1 = (rr * 1024 + kt * 128 + lk * 32) ^ ((rr & 7) << 4);
            float4 x0  = *(const float4*)((const char*)X1s + ob1);
            float4 x1v = *(const float4*)((const char*)X1s + (ob1 ^ 16));
            float fv[8] = {x0.x,x0.y,x0.z,x0.w,x1v.x,x1v.y,x1v.z,x1v.w};
            #pragma unroll
            for (int j = 0; j < 8; ++j) { __bf16 hv=(__bf16)fv[j]; ah[p][j]=hv; al[p][j]=(__bf16)(fv[j]-(float)hv); }
        }
        #pragma unroll
        for (int p = 0; p < 2; ++p)
            #pragma unroll
            for (int nt = 0; nt < 4; ++nt) {
                acc[p][nt] = __builtin_amdgcn_mfma_f32_16x16x32_bf16(ah[p], bh[nt], acc[p][nt], 0, 0, 0);
                acc[p][nt] = __builtin_amdgcn_mfma_f32_16x16x32_bf16(al[p], bh[nt], acc[p][nt], 0, 0, 0);
                acc[p][nt] = __builtin_amdgcn_mfma_f32_16x16x32_bf16(ah[p], bl[nt], acc[p][nt], 0, 0, 0);
            }
    }

    // epilogue 2: bias + elu, dot with uq/uk, reduce over lanes then waves
    float sqp[2][4] = {{0.f,0.f,0.f,0.f},{0.f,0.f,0.f,0.f}};
    float skp[2][4] = {{0.f,0.f,0.f,0.f},{0.f,0.f,0.f,0.f}};
    const float* uq = ws + WS_UQ;
    const float* uk = ws + WS_UK;
    #pragma unroll
    for (int p = 0; p < 2; ++p)
        #pragma unroll
        for (int nt = 0; nt < 4; ++nt) {
            int col = n0 + nt * 16 + lr;
            float bb = b2[col], qc = uq[col], kc = uk[col];
            #pragma unroll
            for (int r = 0; r < 4; ++r) {
                float v = elu1(acc[p][nt][r] + bb);
                sqp[p][r] += v * qc;
                skp[p][r] += v * kc;
            }
        }
    #pragma unroll
    for (int mm = 8; mm >= 1; mm >>= 1) {   // reduce over lr (16-lane groups)
        #pragma unroll
        for (int p = 0; p < 2; ++p)
            #pragma unroll
            for (int r = 0; r < 4; ++r) {
                sqp[p][r] += __shfl_xor(sqp[p][r], mm);
                skp[p][r] += __shfl_xor(skp[p][r], mm);
            }
    }
    if (lr == 0) {
        #pragma unroll
        for (int p = 0; p < 2; ++p)
            #pragma unroll
            for (int r = 0; r < 4; ++r) {
                int rl = p * 16 + lk * 4 + r;
                redq[w * 32 + rl] = sqp[p][r];
                redk[w * 32 + rl] = skp[p][r];
            }
    }
    __syncthreads();
    if (tid < 32) {
        float dq = ws[WS_CONST + 0];
        ws[WS_SQ + rows0 + tid] = redq[tid] + redq[32 + tid] + redq[64 + tid] + redq[96 + tid] + dq;
    } else if (tid < 64) {
        int rl = tid - 32;
        float dk = ws[WS_CONST + 1];
        ws[WS_SK + rows0 + rl] = redk[rl] + redk[32 + rl] + redk[64 + rl] + redk[96 + rl] + dk;
    }
}

// ---------------------------------------------------------------------------
// probs[b,i,j] = sq[b,i] + sk[b,j] + mb   (134 MB write, memory-bound)
// ---------------------------------------------------------------------------
__global__ __launch_bounds__(256) void broadcast_out(const float* __restrict__ ws,
                                                     float* __restrict__ out) {
    __shared__ float skL[2048];
    const int bi = blockIdx.x;
    const int b = bi >> 8;
    const int chunk = bi & 255;
    const int tid = threadIdx.x;

    float4* skL4 = (float4*)skL;
    const float4* skb4 = (const float4*)(ws + WS_SK + b * 2048);
    #pragma unroll
    for (int it = 0; it < 2; ++it) skL4[it * 256 + tid] = skb4[it * 256 + tid];
    __syncthreads();

    const float mb = ws[WS_CONST + 2];
    const int i0 = chunk * 8;
    #pragma unroll
    for (int i = 0; i < 8; ++i) {
        float sval = ws[WS_SQ + b * 2048 + i0 + i] + mb;
        float4* orow = (float4*)(out + ((size_t)(b * 2048 + i0 + i)) * 2048);
        #pragma unroll
        for (int hh = 0; hh < 2; ++hh) {
            int j4 = hh * 256 + tid;
            float4 v = skL4[j4];
            orow[j4] = make_float4(sval + v.x, sval + v.y, sval + v.z, sval + v.w);
        }
    }
}

// ---------------------------------------------------------------------------
extern "C" void kernel_launch(void* const* d_in, const int* in_sizes, int n_in,
                              void* d_out, int out_size, void* d_ws, size_t ws_size,
                              hipStream_t stream) {
    const float* inputs  = (const float*)d_in[0];
    const float* fc1_w   = (const float*)d_in[1];
    const float* fc1_b   = (const float*)d_in[2];
    const float* fc2_w   = (const float*)d_in[3];
    const float* fc2_b   = (const float*)d_in[4];
    const float* bn_g    = (const float*)d_in[5];
    const float* bn_b    = (const float*)d_in[6];
    const float* bn_mean = (const float*)d_in[7];
    const float* bn_var  = (const float*)d_in[8];
    const float* wq_w    = (const float*)d_in[9];
    const float* wq_b    = (const float*)d_in[10];
    const float* wk_w    = (const float*)d_in[11];
    const float* wk_b    = (const float*)d_in[12];
    const float* mlp2_w  = (const float*)d_in[13];
    const float* mlp2_b  = (const float*)d_in[14];
    float* ws  = (float*)d_ws;
    float* out = (float*)d_out;

    hipLaunchKernelGGL(prep_all, dim3(17), dim3(256), 0, stream,
                       fc1_w, fc2_w, bn_g, bn_b, bn_mean, bn_var,
                       wq_w, wq_b, wk_w, wk_b, mlp2_w, mlp2_b, ws);
    hipLaunchKernelGGL(main_mfma, dim3(512), dim3(256), 0, stream,
                       inputs, fc1_b, fc2_b, ws);
    hipLaunchKernelGGL(broadcast_out, dim3(2048), dim3(256), 0, stream, ws, out);
}